// Round 12
// baseline (693.593 us; speedup 1.0000x reference)
//
#include <hip/hip_runtime.h>
#include <stdint.h>

typedef __attribute__((ext_vector_type(4))) float f32x4;
typedef __attribute__((ext_vector_type(8))) __bf16 bf16x8;

#define DEVINL __device__ __forceinline__

// ---------------- sizes ----------------
constexpr int T_LEN = 1024;
constexpr int CDIM  = 2048;
constexpr int MROWS = 2048;               // B*T
constexpr size_t MC = (size_t)MROWS * CDIM;

// ---------------- ws offsets (bytes) ----------------
constexpr size_t SZ_BF  = MC * 2;
constexpr size_t SZ_F32 = MC * 4;
constexpr size_t oXr  = 0;
constexpr size_t oXw  = oXr + SZ_BF;
constexpr size_t oXk  = oXw + SZ_BF;
constexpr size_t oXv  = oXk + SZ_BF;
constexpr size_t oXa  = oXv + SZ_BF;
constexpr size_t oXg  = oXa + SZ_BF;
constexpr size_t oWr  = oXg + SZ_BF;
constexpr size_t oWk  = oWr + SZ_BF;
constexpr size_t oWv  = oWk + SZ_BF;
constexpr size_t oWo  = oWv + SZ_BF;
constexpr size_t oW1T = oWo + SZ_BF;          // [128][2048] bf16 (pad rows>=96 zero)
constexpr size_t oA1T = oW1T + 524288;
constexpr size_t oV1T = oA1T + 524288;        // [128][2048] (pad>=64 zero)
constexpr size_t oG1T = oV1T + 524288;        // [256][2048]
constexpr size_t oW2T = oG1T + 1048576;       // [2048][128] (pad cols>=96 zero)
constexpr size_t oA2T = oW2T + 524288;
constexpr size_t oV2T = oA2T + 524288;
constexpr size_t oG2T = oV2T + 524288;        // [2048][256]
constexpr size_t oHw  = oG2T + 1048576;       // [2048][128] bf16
constexpr size_t oHa  = oHw + 524288;
constexpr size_t oHv  = oHa + 524288;
constexpr size_t oHg  = oHv + 524288;         // [2048][256]
constexpr size_t oR   = oHg + 1048576;        // fp32 [M][C]
constexpr size_t oK   = oR  + SZ_F32;
constexpr size_t oV   = oK  + SZ_F32;
constexpr size_t oWW  = oV  + SZ_F32;
constexpr size_t oAA  = oWW + SZ_F32;
constexpr size_t oBB  = oAA + SZ_F32;
constexpr size_t oG   = oBB + SZ_F32;
constexpr size_t oO   = oG  + SZ_F32;
constexpr size_t oAout= oO  + SZ_F32;         // bf16 [M][C]

// ---------------- helpers ----------------
DEVINL unsigned short f2bf(float f) {
  uint32_t u = __builtin_bit_cast(uint32_t, f);
  u += 0x7fffu + ((u >> 16) & 1u);            // RNE
  return (unsigned short)(u >> 16);
}
DEVINL void st_bf4(unsigned short* p, f32x4 v) {
  ushort4 o;
  o.x = f2bf(v[0]); o.y = f2bf(v[1]); o.z = f2bf(v[2]); o.w = f2bf(v[3]);
  *(ushort4*)p = o;
}
DEVINL void gload16(const void* g, void* l) {
  __builtin_amdgcn_global_load_lds(
      (const __attribute__((address_space(1))) unsigned int*)g,
      (__attribute__((address_space(3))) unsigned int*)l, 16, 0, 0);
}

// ---------------- fp32 -> bf16 convert ----------------
__global__ void k_conv_bf16(const float* __restrict__ s, unsigned short* __restrict__ d, int n4) {
  int i = blockIdx.x * 256 + threadIdx.x;
  if (i >= n4) return;
  f32x4 v = *(const f32x4*)(s + (size_t)i * 4);
  st_bf4(d + (size_t)i * 4, v);
}

// ---------------- transpose + zero-pad, 8 jobs in one launch ----------------
struct TpJobs {
  const float* src[8];
  unsigned short* dst[8];
  int sR[8]; int sC[8]; int dR[8]; int dC[8];
};
__global__ void k_tp8(TpJobs jt) {
  const int j = blockIdx.y;
  const int n = jt.dR[j] * jt.dC[j];
  int i = blockIdx.x * 256 + threadIdx.x;
  if (i >= n) return;
  const int dC = jt.dC[j], sR = jt.sR[j], sC = jt.sC[j];
  int r = i / dC, c = i - r * dC;
  float v = (r < sC && c < sR) ? jt.src[j][(size_t)c * sC + r] : 0.f;
  jt.dst[j][i] = f2bf(v);
}

// ---------------- token shift + 6 mixes -> bf16 ----------------
__global__ void k_mix(const float* __restrict__ x, const float* __restrict__ shift,
                      const float* __restrict__ cr, const float* __restrict__ cw,
                      const float* __restrict__ ck, const float* __restrict__ cv,
                      const float* __restrict__ ca, const float* __restrict__ cg,
                      unsigned short* __restrict__ Xr, unsigned short* __restrict__ Xw,
                      unsigned short* __restrict__ Xk, unsigned short* __restrict__ Xv,
                      unsigned short* __restrict__ Xa, unsigned short* __restrict__ Xg) {
  int i = blockIdx.x * 256 + threadIdx.x;      // one float4 per thread
  size_t e = (size_t)i * 4;
  int m = (int)(e >> 11);
  int c = (int)(e & 2047);
  int t = m & (T_LEN - 1);
  int b = m >> 10;
  f32x4 xc = *(const f32x4*)(x + e);
  f32x4 pv = (t == 0) ? *(const f32x4*)(shift + (size_t)b * CDIM + c)
                      : *(const f32x4*)(x + e - CDIM);
  f32x4 xx = pv - xc;
  st_bf4(Xr + e, xc + xx * (*(const f32x4*)(cr + c)));
  st_bf4(Xw + e, xc + xx * (*(const f32x4*)(cw + c)));
  st_bf4(Xk + e, xc + xx * (*(const f32x4*)(ck + c)));
  st_bf4(Xv + e, xc + xx * (*(const f32x4*)(cv + c)));
  st_bf4(Xa + e, xc + xx * (*(const f32x4*)(ca + c)));
  st_bf4(Xg + e, xc + xx * (*(const f32x4*)(cg + c)));
}

// ---------------- NT bf16 GEMM: C[m][n] = sum_k A[m][k]*B[n][k] ----------------
// m97 structure: 128x128 tile, BK=32, linear [128][32] LDS, global_load_lds w=16,
// 2-barrier loop, 4 waves (2x2 of 64x64), mfma 16x16x32 bf16.
struct GemmJob { const unsigned short* A; const unsigned short* B; void* C; int epi; };
struct GemmBatch { GemmJob j[3]; };

__global__ __launch_bounds__(256) void k_gemm_nt(GemmBatch gb, int K, int ldc) {
  const GemmJob jb = gb.j[blockIdx.z];
  __shared__ __align__(16) unsigned short As[128 * 32];
  __shared__ __align__(16) unsigned short Bs[128 * 32];
  const int tid  = threadIdx.x;
  const int lane = tid & 63;
  const int wv   = tid >> 6;
  const int wm = wv >> 1, wn = wv & 1;
  const int rowB = blockIdx.y * 128;
  const int colB = blockIdx.x * 128;
  // staging: 8 chunks of 1KB (16 rows x 64B); wave wv owns chunks wv and wv+4
  const size_t rsb = (size_t)K * 2;           // row stride bytes
  const int c0 = wv, c1 = wv + 4;
  const char* Ag0 = (const char*)jb.A + (size_t)(rowB + c0 * 16 + (lane >> 2)) * rsb + (lane & 3) * 16;
  const char* Ag1 = (const char*)jb.A + (size_t)(rowB + c1 * 16 + (lane >> 2)) * rsb + (lane & 3) * 16;
  const char* Bg0 = (const char*)jb.B + (size_t)(colB + c0 * 16 + (lane >> 2)) * rsb + (lane & 3) * 16;
  const char* Bg1 = (const char*)jb.B + (size_t)(colB + c1 * 16 + (lane >> 2)) * rsb + (lane & 3) * 16;
  unsigned short* Al0 = As + c0 * 512;        // wave-uniform LDS base
  unsigned short* Al1 = As + c1 * 512;
  unsigned short* Bl0 = Bs + c0 * 512;
  unsigned short* Bl1 = Bs + c1 * 512;
  f32x4 acc[4][4];
#pragma unroll
  for (int mi = 0; mi < 4; ++mi)
#pragma unroll
    for (int ni = 0; ni < 4; ++ni) acc[mi][ni] = (f32x4){0.f, 0.f, 0.f, 0.f};
  const int KT = K >> 5;
  const int fr = lane & 15, fk = (lane >> 4) * 8;
  for (int kt = 0; kt < KT; ++kt) {
    __syncthreads();                          // prior-iter LDS reads complete
    gload16(Ag0, Al0); gload16(Ag1, Al1);
    gload16(Bg0, Bl0); gload16(Bg1, Bl1);
    Ag0 += 64; Ag1 += 64; Bg0 += 64; Bg1 += 64;
    __syncthreads();                          // drains vmcnt -> LDS tile ready
    bf16x8 af[4], bfv[4];
#pragma unroll
    for (int mi = 0; mi < 4; ++mi)
      af[mi] = *(const bf16x8*)&As[(wm * 64 + mi * 16 + fr) * 32 + fk];
#pragma unroll
    for (int ni = 0; ni < 4; ++ni)
      bfv[ni] = *(const bf16x8*)&Bs[(wn * 64 + ni * 16 + fr) * 32 + fk];
#pragma unroll
    for (int mi = 0; mi < 4; ++mi)
#pragma unroll
      for (int ni = 0; ni < 4; ++ni)
        acc[mi][ni] = __builtin_amdgcn_mfma_f32_16x16x32_bf16(af[mi], bfv[ni], acc[mi][ni], 0, 0, 0);
  }
  // epilogue: C/D layout col=lane&15, row=(lane>>4)*4+j
  const int er = (lane >> 4) * 4, ec = lane & 15;
  if (jb.epi == 0) {
    float* Cf = (float*)jb.C;
#pragma unroll
    for (int mi = 0; mi < 4; ++mi)
#pragma unroll
      for (int ni = 0; ni < 4; ++ni) {
        int row0 = rowB + wm * 64 + mi * 16 + er;
        int col  = colB + wn * 64 + ni * 16 + ec;
#pragma unroll
        for (int j = 0; j < 4; ++j)
          Cf[(size_t)(row0 + j) * ldc + col] = acc[mi][ni][j];
      }
  } else {
    unsigned short* Cb = (unsigned short*)jb.C;
#pragma unroll
    for (int mi = 0; mi < 4; ++mi)
#pragma unroll
      for (int ni = 0; ni < 4; ++ni) {
        int row0 = rowB + wm * 64 + mi * 16 + er;
        int col  = colB + wn * 64 + ni * 16 + ec;
#pragma unroll
        for (int j = 0; j < 4; ++j) {
          float val = acc[mi][ni][j];
          if (jb.epi == 2) val = tanhf(val);
          else if (jb.epi == 3) val = 1.f / (1.f + __expf(-val));
          Cb[(size_t)(row0 + j) * ldc + col] = f2bf(val);
        }
      }
  }
}

// ---------------- post-GEMM elementwise + per-head kk normalize ----------------
__global__ __launch_bounds__(256) void k_post(
    float* __restrict__ Kb, float* __restrict__ Vb, float* __restrict__ Wb,
    float* __restrict__ Ab, float* __restrict__ Bb,
    const float* __restrict__ vf, const float* __restrict__ w0,
    const float* __restrict__ a0, const float* __restrict__ v0,
    const float* __restrict__ kkc, const float* __restrict__ kac) {
  int gw = blockIdx.x * 4 + (threadIdx.x >> 6);
  int lane = threadIdx.x & 63;
  int m = gw >> 5, h = gw & 31;
  int c = h * 64 + lane;
  size_t idx = (size_t)m * CDIM + c;
  float kraw = Kb[idx], vraw = Vb[idx], wlr = Wb[idx], alr = Ab[idx], vlr = Bb[idx];
  float z = w0[c] + wlr;
  float sg = 1.f / (1.f + __expf(-z));
  float wdec = __expf(-0.60653065971f * sg);  // exp(-exp(-softplus(-z)-0.5))
  float a = 1.f / (1.f + __expf(-(a0[c] + alr)));
  float vgate = 1.f / (1.f + __expf(-(v0[c] + vlr)));
  float v = vraw + (vf[idx] - vraw) * vgate;
  float kk = kraw * kkc[c];
  float s2 = kk * kk;
#pragma unroll
  for (int off = 32; off; off >>= 1) s2 += __shfl_xor(s2, off);
  float inv = 1.f / fmaxf(sqrtf(s2), 1e-12f);
  kk *= inv;
  float kn = kraw * (1.f + (a - 1.f) * kac[c]);
  Wb[idx] = wdec; Vb[idx] = v; Kb[idx] = kn; Ab[idx] = -kk; Bb[idx] = kk * a;
}

// ---------------- RWKV-7 recurrence ----------------
// R11 skeleton (staging stream / ring algebra / G alternation byte-identical)
// with 16-wide lane geometry on the CONSUME side only:
//   lane: vr = lane&15 (16 v-rows/block), kq = lane>>4 (4 k-groups of 16)
//   => k-reduce = 2 shuffles (xor 16, 32), not 3. 256 blocks (vo in 0..3).
// Shuffles issue FIRST (right after sv partial); slot reads (W/K/B/R/vv + nA
// prefetch for next step) issue after, hiding under shuffle latency (DS pipe
// in-order per wave). Only A is prefetched (consumed at step top). Deferred-o
// retained (R9). All consumed values: registers from LDS reads of the
// unchanged ring -- same change-class as R9/R11 (both PASSED).
__global__ __launch_bounds__(64) void k_scan(
    const float* __restrict__ Rb, const float* __restrict__ Wb,
    const float* __restrict__ Kb, const float* __restrict__ Vb,
    const float* __restrict__ Ab, const float* __restrict__ Bb,
    const float* __restrict__ S0, float* __restrict__ Ob,
    float* __restrict__ Sf) {
  const int bid = blockIdx.x;
  const int bh = bid & 63, vo = bid >> 6;     // vo in 0..3 (grid = 256)
  const int b = bh >> 5, h = bh & 31;
  const int lane = threadIdx.x;
  const int vr = lane & 15;
  const int kq = lane >> 4;
  const int gv = vo * 16 + vr;                // global v-row in head
  const int kk0 = kq * 16;                    // 16 k per lane
  __shared__ __align__(16) float stg[4][6][64];
  const size_t rowBase = (size_t)b * T_LEN * CDIM;
  const size_t colBase = (size_t)h * 64;
  const float* pR = Rb + rowBase + colBase + lane;
  const float* pW = Wb + rowBase + colBase + lane;
  const float* pK = Kb + rowBase + colBase + lane;
  const float* pV = Vb + rowBase + colBase + lane;
  const float* pA = Ab + rowBase + colBase + lane;
  const float* pB = Bb + rowBase + colBase + lane;
  float* Obp = Ob + rowBase + colBase + vo * 16 + lane;  // valid for lane<16
  f32x4 s0, s1, s2, s3;
  {
    const float* sp = S0 + (((size_t)(b * 32 + h)) * 64 + gv) * 64 + kk0;
    s0 = *(const f32x4*)sp;       s1 = *(const f32x4*)(sp + 4);
    s2 = *(const f32x4*)(sp + 8); s3 = *(const f32x4*)(sp + 12);
  }
  float gA[6], gB[6];
  {   // prologue: stg[0]<-t0, stg[1]<-t1, gA<-t2, gB<-t3   (R11-exact)
    float h0[6], h1[6];
    h0[0] = pR[0]; h0[1] = pW[0]; h0[2] = pK[0]; h0[3] = pV[0]; h0[4] = pA[0]; h0[5] = pB[0];
    h1[0] = pR[CDIM]; h1[1] = pW[CDIM]; h1[2] = pK[CDIM]; h1[3] = pV[CDIM]; h1[4] = pA[CDIM]; h1[5] = pB[CDIM];
#pragma unroll
    for (int j = 0; j < 6; ++j) { stg[0][j][lane] = h0[j]; stg[1][j][lane] = h1[j]; }
    gA[0] = pR[2 * CDIM]; gA[1] = pW[2 * CDIM]; gA[2] = pK[2 * CDIM];
    gA[3] = pV[2 * CDIM]; gA[4] = pA[2 * CDIM]; gA[5] = pB[2 * CDIM];
    gB[0] = pR[3 * CDIM]; gB[1] = pW[3 * CDIM]; gB[2] = pK[3 * CDIM];
    gB[3] = pV[3 * CDIM]; gB[4] = pA[3 * CDIM]; gB[5] = pB[3 * CDIM];
  }
  // prefetched A-operand for step 0 (slot 0, written in prologue)
  f32x4 nA0 = *(const f32x4*)&stg[0][4][kk0];
  f32x4 nA1 = *(const f32x4*)&stg[0][4][kk0 + 4];
  f32x4 nA2 = *(const f32x4*)&stg[0][4][kk0 + 8];
  f32x4 nA3 = *(const f32x4*)&stg[0][4][kk0 + 12];
  float pox = 0.f;                            // deferred o partial (prev step)
#define SCAN_STEP(T, G, FIRST) do {                                            \
    const int _sl = (T) & 3;                                                   \
    f32x4 _sva = nA0 * s0 + nA1 * s1;                                          \
    f32x4 _svb = nA2 * s2 + nA3 * s3;                                          \
    f32x4 _sv = _sva + _svb;                                                   \
    float _sa = _sv[0] + _sv[1] + _sv[2] + _sv[3];                             \
    float _po = pox;                                                           \
    _sa += __shfl_xor(_sa, 16); _po += __shfl_xor(_po, 16);                    \
    _sa += __shfl_xor(_sa, 32); _po += __shfl_xor(_po, 32);                    \
    const f32x4 _w0 = *(const f32x4*)&stg[_sl][1][kk0];                        \
    const f32x4 _w1 = *(const f32x4*)&stg[_sl][1][kk0 + 4];                    \
    const f32x4 _w2 = *(const f32x4*)&stg[_sl][1][kk0 + 8];                    \
    const f32x4 _w3 = *(const f32x4*)&stg[_sl][1][kk0 + 12];                   \
    const f32x4 _k0 = *(const f32x4*)&stg[_sl][2][kk0];                        \
    const f32x4 _k1 = *(const f32x4*)&stg[_sl][2][kk0 + 4];                    \
    const f32x4 _k2 = *(const f32x4*)&stg[_sl][2][kk0 + 8];                    \
    const f32x4 _k3 = *(const f32x4*)&stg[_sl][2][kk0 + 12];                   \
    const f32x4 _b0 = *(const f32x4*)&stg[_sl][5][kk0];                        \
    const f32x4 _b1 = *(const f32x4*)&stg[_sl][5][kk0 + 4];                    \
    const f32x4 _b2 = *(const f32x4*)&stg[_sl][5][kk0 + 8];                    \
    const f32x4 _b3 = *(const f32x4*)&stg[_sl][5][kk0 + 12];                   \
    const float _vv = stg[_sl][3][gv];                                         \
    const f32x4 _r0 = *(const f32x4*)&stg[_sl][0][kk0];                        \
    const f32x4 _r1 = *(const f32x4*)&stg[_sl][0][kk0 + 4];                    \
    const f32x4 _r2 = *(const f32x4*)&stg[_sl][0][kk0 + 8];                    \
    const f32x4 _r3 = *(const f32x4*)&stg[_sl][0][kk0 + 12];                   \
    { const int _np = ((T) + 1) & 3;        /* prefetch next-step A */         \
      nA0 = *(const f32x4*)&stg[_np][4][kk0];                                  \
      nA1 = *(const f32x4*)&stg[_np][4][kk0 + 4];                              \
      nA2 = *(const f32x4*)&stg[_np][4][kk0 + 8];                              \
      nA3 = *(const f32x4*)&stg[_np][4][kk0 + 12]; }                           \
    if (!(FIRST) && lane < 16) Obp[(size_t)((T) - 1) * CDIM] = _po;            \
    { const int _ws = ((T) + 2) & 3;                                           \
      stg[_ws][0][lane] = G[0]; stg[_ws][1][lane] = G[1];                      \
      stg[_ws][2][lane] = G[2]; stg[_ws][3][lane] = G[3];                      \
      stg[_ws][4][lane] = G[4]; stg[_ws][5][lane] = G[5];                      \
      const size_t _to = (size_t)(((T) + 4 < T_LEN) ? (T) + 4 : T_LEN - 1) * CDIM; \
      G[0] = pR[_to]; G[1] = pW[_to]; G[2] = pK[_to];                          \
      G[3] = pV[_to]; G[4] = pA[_to]; G[5] = pB[_to]; }                        \
    s0 = s0 * _w0 + _sa * _b0 + _vv * _k0;                                     \
    s1 = s1 * _w1 + _sa * _b1 + _vv * _k1;                                     \
    s2 = s2 * _w2 + _sa * _b2 + _vv * _k2;                                     \
    s3 = s3 * _w3 + _sa * _b3 + _vv * _k3;                                     \
    f32x4 _ova = s0 * _r0 + s1 * _r1;                                          \
    f32x4 _ovb = s2 * _r2 + s3 * _r3;                                          \
    f32x4 _ov = _ova + _ovb;                                                   \
    pox = _ov[0] + _ov[1] + _ov[2] + _ov[3];                                   \
  } while (0)
  SCAN_STEP(0, gA, true);
  SCAN_STEP(1, gB, false);
  for (int t = 2; t < T_LEN; t += 2) {
    SCAN_STEP(t, gA, false);
    SCAN_STEP(t + 1, gB, false);
  }
#undef SCAN_STEP
  {   // flush o_{T_LEN-1}
    float _po = pox;
    _po += __shfl_xor(_po, 16);
    _po += __shfl_xor(_po, 32);
    if (lane < 16) Obp[(size_t)(T_LEN - 1) * CDIM] = _po;
  }
  float* sfp = Sf + (((size_t)(b * 32 + h)) * 64 + gv) * 64 + kk0;
  *(f32x4*)sfp = s0; *(f32x4*)(sfp + 4) = s1;
  *(f32x4*)(sfp + 8) = s2; *(f32x4*)(sfp + 12) = s3;
}

// ---------------- GroupNorm + bonus + gate -> bf16 A for out-proj ----------------
__global__ __launch_bounds__(256) void k_gn(
    const float* __restrict__ Ob, const float* __restrict__ Rb,
    const float* __restrict__ Kb, const float* __restrict__ Vb,
    const float* __restrict__ Gb, const float* __restrict__ rk,
    const float* __restrict__ gw, const float* __restrict__ gb2,
    unsigned short* __restrict__ Aout) {
  int gwv = blockIdx.x * 4 + (threadIdx.x >> 6);
  int lane = threadIdx.x & 63;
  int m = gwv >> 5, h = gwv & 31;
  int c = h * 64 + lane;
  size_t idx = (size_t)m * CDIM + c;
  float o = Ob[idx], r = Rb[idx], k = Kb[idx], v = Vb[idx], g = Gb[idx];
  float t1 = o, t2 = o * o, t3 = r * k * rk[c];
#pragma unroll
  for (int off = 32; off; off >>= 1) {
    t1 += __shfl_xor(t1, off);
    t2 += __shfl_xor(t2, off);
    t3 += __shfl_xor(t3, off);
  }
  float mean = t1 * (1.f / 64.f);
  float var = t2 * (1.f / 64.f) - mean * mean;
  float og = (o - mean) * rsqrtf(var + 6.4e-4f) * gw[c] + gb2[c];  // eps=1e-5*64
  og += t3 * v;
  Aout[idx] = f2bf(og * g);
}

// ---------------- launch ----------------
extern "C" void kernel_launch(void* const* d_in, const int* in_sizes, int n_in,
                              void* d_out, int out_size, void* d_ws, size_t ws_size,
                              hipStream_t stream) {
  (void)in_sizes; (void)n_in; (void)out_size; (void)ws_size;
  const float* x      = (const float*)d_in[0];
  const float* vfirst = (const float*)d_in[1];
  const float* shift  = (const float*)d_in[2];
  const float* wkv0   = (const float*)d_in[3];
  const float* xr_c   = (const float*)d_in[4];
  const float* xw_c   = (const float*)d_in[5];
  const float* xk_c   = (const float*)d_in[6];
  const float* xv_c   = (const float*)d_in[7];
  const float* xa_c   = (const float*)d_in[8];
  const float* xg_c   = (const float*)d_in[9];
  const float* w0     = (const float*)d_in[10];
  const float* w1     = (const float*)d_in[11];
  const float* w2     = (const float*)d_in[12];
  const float* a0     = (const float*)d_in[13];
  const float* a1     = (const float*)d_in[14];
  const float* a2     = (const float*)d_in[15];
  const float* v0     = (const float*)d_in[16];
  const float* v1     = (const float*)d_in[17];
  const float* v2     = (const float*)d_in[18];
  const float* g1     = (const float*)d_in[19];
  const float* g2     = (const float*)d_in[20];
  const float* k_k    = (const float*)d_in[21];
  const float* k_a    = (const float*)d_in[22];
  const float* r_k    = (const float*)d_in[23];
  const float* W_r    = (const float*)d_in[24];
  const float* W_k    = (const float*)d_in[25];
  const float* W_v    = (const float*)d_in[26];
  const float* W_o    = (const float*)d_in[27];
  const float* gn_w   = (const float*)d_in[28];
  const float* gn_b   = (const float*)d_in[29];
  char* ws = (char*)d_ws;
  auto BF = [&](size_t o) { return (unsigned short*)(ws + o); };
  auto FP = [&](size_t o) { return (float*)(ws + o); };

  // weights -> bf16
  k_conv_bf16<<<4096, 256, 0, stream>>>(W_r, BF(oWr), 1048576);
  k_conv_bf16<<<4096, 256, 0, stream>>>(W_k, BF(oWk), 1048576);
  k_conv_bf16<<<4096, 256, 0, stream>>>(W_v, BF(oWv), 1048576);
  k_conv_bf16<<<4096, 256, 0, stream>>>(W_o, BF(oWo), 1048576);
  // small weights -> transposed, zero-padded bf16 (8 jobs, one launch)
  { TpJobs jt{};
    jt.src[0] = w1; jt.dst[0] = BF(oW1T); jt.sR[0] = 2048; jt.sC[0] = 96;   jt.dR[0] = 128;  jt.dC[0] = 2048;
    jt.src[1] = a1; jt.dst[1] = BF(oA1T); jt.sR[1] = 2048; jt.sC[1] = 96;   jt.dR[1] = 128;  jt.dC[1] = 2048;
    jt.src[2] = v1; jt.dst[2] = BF(oV1T); jt.sR[2] = 2048; jt.sC[2] = 64;   jt.dR[2] = 128;  jt.dC[2] = 2048;
    jt.src[3] = g1; jt.dst[3] = BF(oG1T); jt.sR[3] = 2048; jt.sC[3] = 256;  jt.dR[3] = 256;  jt.dC[3] = 2048;
    jt.src[4] = w2; jt.dst[4] = BF(oW2T); jt.sR[4] = 96;   jt.sC[4] = 2048; jt.dR[4] = 2048; jt.dC[4] = 128;
    jt.src[5] = a2; jt.dst[5] = BF(oA2T); jt.sR[5] = 96;   jt.sC[5] = 2048; jt.dR[5] = 2048; jt.dC[5] = 128;
    jt.src[6] = v2; jt.dst[6] = BF(oV2T); jt.sR[6] = 64;   jt.sC[6] = 2048; jt.dR[6] = 2048; jt.dC[6] = 128;
    jt.src[7] = g2; jt.dst[7] = BF(oG2T); jt.sR[7] = 256;  jt.sC[7] = 2048; jt.dR[7] = 2048; jt.dC[7] = 256;
    k_tp8<<<dim3(2048, 8), 256, 0, stream>>>(jt); }
  // token shift + mixes
  k_mix<<<4096, 256, 0, stream>>>(x, shift, xr_c, xw_c, xk_c, xv_c, xa_c, xg_c,
                                  BF(oXr), BF(oXw), BF(oXk), BF(oXv), BF(oXa), BF(oXg));
  // r, k, v projections (batched via blockIdx.z)
  { GemmBatch gb{};
    gb.j[0] = {BF(oXr), BF(oWr), FP(oR), 0};
    gb.j[1] = {BF(oXk), BF(oWk), FP(oK), 0};
    gb.j[2] = {BF(oXv), BF(oWv), FP(oV), 0};
    k_gemm_nt<<<dim3(16, 16, 3), 256, 0, stream>>>(gb, 2048, 2048); }
  // low-rank stage 1 (N padded to 128)
  { GemmBatch gb{};
    gb.j[0] = {BF(oXw), BF(oW1T), BF(oHw), 2};   // tanh
    gb.j[1] = {BF(oXa), BF(oA1T), BF(oHa), 1};
    gb.j[2] = {BF(oXv), BF(oV1T), BF(oHv), 1};
    k_gemm_nt<<<dim3(1, 16, 3), 256, 0, stream>>>(gb, 2048, 128); }
  // gate stage 1 (N=256, sigmoid)
  { GemmBatch gb{};
    gb.j[0] = {BF(oXg), BF(oG1T), BF(oHg), 3};
    k_gemm_nt<<<dim3(2, 16, 1), 256, 0, stream>>>(gb, 2048, 256); }
  // low-rank stage 2 (K=128)
  { GemmBatch gb{};
    gb.j[0] = {BF(oHw), BF(oW2T), FP(oWW), 0};
    gb.j[1] = {BF(oHa), BF(oA2T), FP(oAA), 0};
    gb.j[2] = {BF(oHv), BF(oV2T), FP(oBB), 0};
    k_gemm_nt<<<dim3(16, 16, 3), 256, 0, stream>>>(gb, 128, 2048); }
  // gate stage 2 (K=256)
  { GemmBatch gb{};
    gb.j[0] = {BF(oHg), BF(oG2T), FP(oG), 0};
    k_gemm_nt<<<dim3(16, 16, 1), 256, 0, stream>>>(gb, 256, 2048); }
  // elementwise post (decay, a, v-blend, kk-normalize, k update)
  k_post<<<16384, 256, 0, stream>>>(FP(oK), FP(oV), FP(oWW), FP(oAA), FP(oBB),
                                    vfirst, w0, a0, v0, k_k, k_a);
  // recurrence: 256 single-wave blocks (16 v-rows each)
  k_scan<<<256, 64, 0, stream>>>(FP(oR), FP(oWW), FP(oK), FP(oV), FP(oAA), FP(oBB),
                                 wkv0, FP(oO), (float*)d_out + MC);
  // groupnorm + bonus + gate
  k_gn<<<16384, 256, 0, stream>>>(FP(oO), FP(oR), FP(oK), FP(oV), FP(oG),
                                  r_k, gn_w, gn_b, BF(oAout));
  // output projection -> d_out
  { GemmBatch gb{};
    gb.j[0] = {BF(oAout), BF(oWo), d_out, 0};
    k_gemm_nt<<<dim3(16, 16, 1), 256, 0, stream>>>(gb, 2048, 2048); }
}

// Round 13
// 594.030 us; speedup vs baseline: 1.1676x; 1.1676x over previous
//
#include <hip/hip_runtime.h>
#include <stdint.h>

typedef __attribute__((ext_vector_type(4))) float f32x4;
typedef __attribute__((ext_vector_type(8))) __bf16 bf16x8;

#define DEVINL __device__ __forceinline__

// ---------------- sizes ----------------
constexpr int T_LEN = 1024;
constexpr int CDIM  = 2048;
constexpr int MROWS = 2048;               // B*T
constexpr size_t MC = (size_t)MROWS * CDIM;

// ---------------- ws offsets (bytes) ----------------
constexpr size_t SZ_BF  = MC * 2;
constexpr size_t SZ_F32 = MC * 4;
constexpr size_t oXr  = 0;
constexpr size_t oXw  = oXr + SZ_BF;
constexpr size_t oXk  = oXw + SZ_BF;
constexpr size_t oXv  = oXk + SZ_BF;
constexpr size_t oXa  = oXv + SZ_BF;
constexpr size_t oXg  = oXa + SZ_BF;
constexpr size_t oWr  = oXg + SZ_BF;
constexpr size_t oWk  = oWr + SZ_BF;
constexpr size_t oWv  = oWk + SZ_BF;
constexpr size_t oWo  = oWv + SZ_BF;
constexpr size_t oW1T = oWo + SZ_BF;          // [128][2048] bf16 (pad rows>=96 zero)
constexpr size_t oA1T = oW1T + 524288;
constexpr size_t oV1T = oA1T + 524288;        // [128][2048] (pad>=64 zero)
constexpr size_t oG1T = oV1T + 524288;        // [256][2048]
constexpr size_t oW2T = oG1T + 1048576;       // [2048][128] (pad cols>=96 zero)
constexpr size_t oA2T = oW2T + 524288;
constexpr size_t oV2T = oA2T + 524288;
constexpr size_t oG2T = oV2T + 524288;        // [2048][256]
constexpr size_t oHw  = oG2T + 1048576;       // [2048][128] bf16
constexpr size_t oHa  = oHw + 524288;
constexpr size_t oHv  = oHa + 524288;
constexpr size_t oHg  = oHv + 524288;         // [2048][256]
constexpr size_t oR   = oHg + 1048576;        // fp32 [M][C]
constexpr size_t oK   = oR  + SZ_F32;
constexpr size_t oV   = oK  + SZ_F32;
constexpr size_t oWW  = oV  + SZ_F32;
constexpr size_t oAA  = oWW + SZ_F32;
constexpr size_t oBB  = oAA + SZ_F32;
constexpr size_t oG   = oBB + SZ_F32;
constexpr size_t oO   = oG  + SZ_F32;
constexpr size_t oAout= oO  + SZ_F32;         // bf16 [M][C]

// ---------------- helpers ----------------
DEVINL unsigned short f2bf(float f) {
  uint32_t u = __builtin_bit_cast(uint32_t, f);
  u += 0x7fffu + ((u >> 16) & 1u);            // RNE
  return (unsigned short)(u >> 16);
}
DEVINL void st_bf4(unsigned short* p, f32x4 v) {
  ushort4 o;
  o.x = f2bf(v[0]); o.y = f2bf(v[1]); o.z = f2bf(v[2]); o.w = f2bf(v[3]);
  *(ushort4*)p = o;
}
DEVINL void gload16(const void* g, void* l) {
  __builtin_amdgcn_global_load_lds(
      (const __attribute__((address_space(1))) unsigned int*)g,
      (__attribute__((address_space(3))) unsigned int*)l, 16, 0, 0);
}

// ---------------- fp32 -> bf16 convert, 4 matrices per launch ----------------
// grid (4096, 4), n4 = 1048576 float4-chunks PER matrix (2048*2048/4).
struct Conv4 { const float* s0; const float* s1; const float* s2; const float* s3;
               unsigned short* d0; unsigned short* d1; unsigned short* d2; unsigned short* d3; };
__global__ void k_conv4(Conv4 c, int n4) {
  int i = blockIdx.x * 256 + threadIdx.x;
  if (i >= n4) return;
  const float* s = (blockIdx.y == 0) ? c.s0 : (blockIdx.y == 1) ? c.s1
                   : (blockIdx.y == 2) ? c.s2 : c.s3;
  unsigned short* d = (blockIdx.y == 0) ? c.d0 : (blockIdx.y == 1) ? c.d1
                      : (blockIdx.y == 2) ? c.d2 : c.d3;
  f32x4 v = *(const f32x4*)(s + (size_t)i * 4);
  st_bf4(d + (size_t)i * 4, v);
}

// ---------------- transpose + zero-pad, 8 jobs in one launch ----------------
struct TpJobs {
  const float* src[8];
  unsigned short* dst[8];
  int sR[8]; int sC[8]; int dR[8]; int dC[8];
};
__global__ void k_tp8(TpJobs jt) {
  const int j = blockIdx.y;
  const int n = jt.dR[j] * jt.dC[j];
  int i = blockIdx.x * 256 + threadIdx.x;
  if (i >= n) return;
  const int dC = jt.dC[j], sR = jt.sR[j], sC = jt.sC[j];
  int r = i / dC, c = i - r * dC;
  float v = (r < sC && c < sR) ? jt.src[j][(size_t)c * sC + r] : 0.f;
  jt.dst[j][i] = f2bf(v);
}

// ---------------- token shift + 6 mixes -> bf16 ----------------
__global__ void k_mix(const float* __restrict__ x, const float* __restrict__ shift,
                      const float* __restrict__ cr, const float* __restrict__ cw,
                      const float* __restrict__ ck, const float* __restrict__ cv,
                      const float* __restrict__ ca, const float* __restrict__ cg,
                      unsigned short* __restrict__ Xr, unsigned short* __restrict__ Xw,
                      unsigned short* __restrict__ Xk, unsigned short* __restrict__ Xv,
                      unsigned short* __restrict__ Xa, unsigned short* __restrict__ Xg) {
  int i = blockIdx.x * 256 + threadIdx.x;      // one float4 per thread
  size_t e = (size_t)i * 4;
  int m = (int)(e >> 11);
  int c = (int)(e & 2047);
  int t = m & (T_LEN - 1);
  int b = m >> 10;
  f32x4 xc = *(const f32x4*)(x + e);
  f32x4 pv = (t == 0) ? *(const f32x4*)(shift + (size_t)b * CDIM + c)
                      : *(const f32x4*)(x + e - CDIM);
  f32x4 xx = pv - xc;
  st_bf4(Xr + e, xc + xx * (*(const f32x4*)(cr + c)));
  st_bf4(Xw + e, xc + xx * (*(const f32x4*)(cw + c)));
  st_bf4(Xk + e, xc + xx * (*(const f32x4*)(ck + c)));
  st_bf4(Xv + e, xc + xx * (*(const f32x4*)(cv + c)));
  st_bf4(Xa + e, xc + xx * (*(const f32x4*)(ca + c)));
  st_bf4(Xg + e, xc + xx * (*(const f32x4*)(cg + c)));
}

// ---------------- NT bf16 GEMM: C[m][n] = sum_k A[m][k]*B[n][k] ----------------
// m97 structure: 128x128 tile, BK=32, linear [128][32] LDS, global_load_lds w=16,
// 2-barrier loop, 4 waves (2x2 of 64x64), mfma 16x16x32 bf16.
// Per-job ldc/n; blocks with colB >= n early-exit (lets jobs of different N batch).
struct GemmJob { const unsigned short* A; const unsigned short* B; void* C; int epi; int ldc; int n; };
struct GemmBatch { GemmJob j[4]; };

__global__ __launch_bounds__(256) void k_gemm_nt(GemmBatch gb, int K) {
  const GemmJob jb = gb.j[blockIdx.z];
  const int colB = blockIdx.x * 128;
  if (colB >= jb.n) return;
  const int ldc = jb.ldc;
  __shared__ __align__(16) unsigned short As[128 * 32];
  __shared__ __align__(16) unsigned short Bs[128 * 32];
  const int tid  = threadIdx.x;
  const int lane = tid & 63;
  const int wv   = tid >> 6;
  const int wm = wv >> 1, wn = wv & 1;
  const int rowB = blockIdx.y * 128;
  // staging: 8 chunks of 1KB (16 rows x 64B); wave wv owns chunks wv and wv+4
  const size_t rsb = (size_t)K * 2;           // row stride bytes
  const int c0 = wv, c1 = wv + 4;
  const char* Ag0 = (const char*)jb.A + (size_t)(rowB + c0 * 16 + (lane >> 2)) * rsb + (lane & 3) * 16;
  const char* Ag1 = (const char*)jb.A + (size_t)(rowB + c1 * 16 + (lane >> 2)) * rsb + (lane & 3) * 16;
  const char* Bg0 = (const char*)jb.B + (size_t)(colB + c0 * 16 + (lane >> 2)) * rsb + (lane & 3) * 16;
  const char* Bg1 = (const char*)jb.B + (size_t)(colB + c1 * 16 + (lane >> 2)) * rsb + (lane & 3) * 16;
  unsigned short* Al0 = As + c0 * 512;        // wave-uniform LDS base
  unsigned short* Al1 = As + c1 * 512;
  unsigned short* Bl0 = Bs + c0 * 512;
  unsigned short* Bl1 = Bs + c1 * 512;
  f32x4 acc[4][4];
#pragma unroll
  for (int mi = 0; mi < 4; ++mi)
#pragma unroll
    for (int ni = 0; ni < 4; ++ni) acc[mi][ni] = (f32x4){0.f, 0.f, 0.f, 0.f};
  const int KT = K >> 5;
  const int fr = lane & 15, fk = (lane >> 4) * 8;
  for (int kt = 0; kt < KT; ++kt) {
    __syncthreads();                          // prior-iter LDS reads complete
    gload16(Ag0, Al0); gload16(Ag1, Al1);
    gload16(Bg0, Bl0); gload16(Bg1, Bl1);
    Ag0 += 64; Ag1 += 64; Bg0 += 64; Bg1 += 64;
    __syncthreads();                          // drains vmcnt -> LDS tile ready
    bf16x8 af[4], bfv[4];
#pragma unroll
    for (int mi = 0; mi < 4; ++mi)
      af[mi] = *(const bf16x8*)&As[(wm * 64 + mi * 16 + fr) * 32 + fk];
#pragma unroll
    for (int ni = 0; ni < 4; ++ni)
      bfv[ni] = *(const bf16x8*)&Bs[(wn * 64 + ni * 16 + fr) * 32 + fk];
#pragma unroll
    for (int mi = 0; mi < 4; ++mi)
#pragma unroll
      for (int ni = 0; ni < 4; ++ni)
        acc[mi][ni] = __builtin_amdgcn_mfma_f32_16x16x32_bf16(af[mi], bfv[ni], acc[mi][ni], 0, 0, 0);
  }
  // epilogue: C/D layout col=lane&15, row=(lane>>4)*4+j
  const int er = (lane >> 4) * 4, ec = lane & 15;
  if (jb.epi == 0) {
    float* Cf = (float*)jb.C;
#pragma unroll
    for (int mi = 0; mi < 4; ++mi)
#pragma unroll
      for (int ni = 0; ni < 4; ++ni) {
        int row0 = rowB + wm * 64 + mi * 16 + er;
        int col  = colB + wn * 64 + ni * 16 + ec;
#pragma unroll
        for (int j = 0; j < 4; ++j)
          Cf[(size_t)(row0 + j) * ldc + col] = acc[mi][ni][j];
      }
  } else {
    unsigned short* Cb = (unsigned short*)jb.C;
#pragma unroll
    for (int mi = 0; mi < 4; ++mi)
#pragma unroll
      for (int ni = 0; ni < 4; ++ni) {
        int row0 = rowB + wm * 64 + mi * 16 + er;
        int col  = colB + wn * 64 + ni * 16 + ec;
#pragma unroll
        for (int j = 0; j < 4; ++j) {
          float val = acc[mi][ni][j];
          if (jb.epi == 2) val = tanhf(val);
          else if (jb.epi == 3) val = 1.f / (1.f + __expf(-val));
          Cb[(size_t)(row0 + j) * ldc + col] = f2bf(val);
        }
      }
  }
}

// ---------------- post-GEMM elementwise + per-head kk normalize ----------------
__global__ __launch_bounds__(256) void k_post(
    float* __restrict__ Kb, float* __restrict__ Vb, float* __restrict__ Wb,
    float* __restrict__ Ab, float* __restrict__ Bb,
    const float* __restrict__ vf, const float* __restrict__ w0,
    const float* __restrict__ a0, const float* __restrict__ v0,
    const float* __restrict__ kkc, const float* __restrict__ kac) {
  int gw = blockIdx.x * 4 + (threadIdx.x >> 6);
  int lane = threadIdx.x & 63;
  int m = gw >> 5, h = gw & 31;
  int c = h * 64 + lane;
  size_t idx = (size_t)m * CDIM + c;
  float kraw = Kb[idx], vraw = Vb[idx], wlr = Wb[idx], alr = Ab[idx], vlr = Bb[idx];
  float z = w0[c] + wlr;
  float sg = 1.f / (1.f + __expf(-z));
  float wdec = __expf(-0.60653065971f * sg);  // exp(-exp(-softplus(-z)-0.5))
  float a = 1.f / (1.f + __expf(-(a0[c] + alr)));
  float vgate = 1.f / (1.f + __expf(-(v0[c] + vlr)));
  float v = vraw + (vf[idx] - vraw) * vgate;
  float kk = kraw * kkc[c];
  float s2 = kk * kk;
#pragma unroll
  for (int off = 32; off; off >>= 1) s2 += __shfl_xor(s2, off);
  float inv = 1.f / fmaxf(sqrtf(s2), 1e-12f);
  kk *= inv;
  float kn = kraw * (1.f + (a - 1.f) * kac[c]);
  Wb[idx] = wdec; Vb[idx] = v; Kb[idx] = kn; Ab[idx] = -kk; Bb[idx] = kk * a;
}

// ---------------- RWKV-7 recurrence (R11-exact, PASSING @293us) ----------------
__global__ __launch_bounds__(64) void k_scan(
    const float* __restrict__ Rb, const float* __restrict__ Wb,
    const float* __restrict__ Kb, const float* __restrict__ Vb,
    const float* __restrict__ Ab, const float* __restrict__ Bb,
    const float* __restrict__ S0, float* __restrict__ Ob,
    float* __restrict__ Sf) {
  const int bid = blockIdx.x;
  const int bh = bid & 63, vo = bid >> 6;     // vo stride 64 => same XCD as its head
  const int b = bh >> 5, h = bh & 31;
  const int lane = threadIdx.x;
  const int vr = lane & 7;
  const int kq = lane >> 3;
  const int gv = vo * 8 + vr;                 // global v-row in head
  const int kk0 = kq * 8;
  __shared__ __align__(16) float stg[4][6][64];
  const size_t rowBase = (size_t)b * T_LEN * CDIM;
  const size_t colBase = (size_t)h * 64;
  const float* pR = Rb + rowBase + colBase + lane;
  const float* pW = Wb + rowBase + colBase + lane;
  const float* pK = Kb + rowBase + colBase + lane;
  const float* pV = Vb + rowBase + colBase + lane;
  const float* pA = Ab + rowBase + colBase + lane;
  const float* pB = Bb + rowBase + colBase + lane;
  float* Obp = Ob + rowBase + colBase + vo * 8 + lane;   // valid for lane<8
  f32x4 s0, s1;
  {
    const float* sp = S0 + (((size_t)(b * 32 + h)) * 64 + gv) * 64 + kk0;
    s0 = *(const f32x4*)sp; s1 = *(const f32x4*)(sp + 4);
  }
  float gA[6], gB[6];
  {   // prologue: stg[0]<-t0, stg[1]<-t1, gA<-t2, gB<-t3
    float h0[6], h1[6];
    h0[0] = pR[0]; h0[1] = pW[0]; h0[2] = pK[0]; h0[3] = pV[0]; h0[4] = pA[0]; h0[5] = pB[0];
    h1[0] = pR[CDIM]; h1[1] = pW[CDIM]; h1[2] = pK[CDIM]; h1[3] = pV[CDIM]; h1[4] = pA[CDIM]; h1[5] = pB[CDIM];
#pragma unroll
    for (int j = 0; j < 6; ++j) { stg[0][j][lane] = h0[j]; stg[1][j][lane] = h1[j]; }
    gA[0] = pR[2 * CDIM]; gA[1] = pW[2 * CDIM]; gA[2] = pK[2 * CDIM];
    gA[3] = pV[2 * CDIM]; gA[4] = pA[2 * CDIM]; gA[5] = pB[2 * CDIM];
    gB[0] = pR[3 * CDIM]; gB[1] = pW[3 * CDIM]; gB[2] = pK[3 * CDIM];
    gB[3] = pV[3 * CDIM]; gB[4] = pA[3 * CDIM]; gB[5] = pB[3 * CDIM];
  }
  // operand register sets: a-set = even steps, b-set = odd steps
  f32x4 aR0, aR1, aW0, aW1, aK0, aK1, aA0, aA1, aB0, aB1; float aVV;
  f32x4 bR0, bR1, bW0, bW1, bK0, bK1, bA0, bA1, bB0, bB1; float bVV;
  // init a-set <- slot 0 (t0), written in prologue (in-order DS)
  aR0 = *(const f32x4*)&stg[0][0][kk0]; aR1 = *(const f32x4*)&stg[0][0][kk0 + 4];
  aW0 = *(const f32x4*)&stg[0][1][kk0]; aW1 = *(const f32x4*)&stg[0][1][kk0 + 4];
  aK0 = *(const f32x4*)&stg[0][2][kk0]; aK1 = *(const f32x4*)&stg[0][2][kk0 + 4];
  aA0 = *(const f32x4*)&stg[0][4][kk0]; aA1 = *(const f32x4*)&stg[0][4][kk0 + 4];
  aB0 = *(const f32x4*)&stg[0][5][kk0]; aB1 = *(const f32x4*)&stg[0][5][kk0 + 4];
  aVV = stg[0][3][gv];
  float pox = 0.f;                            // deferred o partial (prev step)
#define SCAN_STEP(T, G, SR0,SR1,SW0,SW1,SK0,SK1,SA0,SA1,SB0,SB1,SVV,           \
                  NR0,NR1,NW0,NW1,NK0,NK1,NA0,NA1,NB0,NB1,NVV, FIRST) do {     \
    f32x4 _sv = SA0 * s0 + SA1 * s1;                                           \
    float _sa = _sv[0] + _sv[1] + _sv[2] + _sv[3];                             \
    { const int _np = ((T) + 1) & 3;        /* prefetch next-step operands */  \
      NR0 = *(const f32x4*)&stg[_np][0][kk0]; NR1 = *(const f32x4*)&stg[_np][0][kk0 + 4]; \
      NW0 = *(const f32x4*)&stg[_np][1][kk0]; NW1 = *(const f32x4*)&stg[_np][1][kk0 + 4]; \
      NK0 = *(const f32x4*)&stg[_np][2][kk0]; NK1 = *(const f32x4*)&stg[_np][2][kk0 + 4]; \
      NA0 = *(const f32x4*)&stg[_np][4][kk0]; NA1 = *(const f32x4*)&stg[_np][4][kk0 + 4]; \
      NB0 = *(const f32x4*)&stg[_np][5][kk0]; NB1 = *(const f32x4*)&stg[_np][5][kk0 + 4]; \
      NVV = stg[_np][3][gv]; }                                                 \
    float _po = pox;                                                           \
    _sa += __shfl_xor(_sa, 8);  _po += __shfl_xor(_po, 8);                     \
    _sa += __shfl_xor(_sa, 16); _po += __shfl_xor(_po, 16);                    \
    _sa += __shfl_xor(_sa, 32); _po += __shfl_xor(_po, 32);                    \
    if (!(FIRST) && lane < 8) Obp[(size_t)((T) - 1) * CDIM] = _po;             \
    { const int _ws = ((T) + 2) & 3;                                           \
      stg[_ws][0][lane] = G[0]; stg[_ws][1][lane] = G[1];                      \
      stg[_ws][2][lane] = G[2]; stg[_ws][3][lane] = G[3];                      \
      stg[_ws][4][lane] = G[4]; stg[_ws][5][lane] = G[5];                      \
      const size_t _to = (size_t)(((T) + 4 < T_LEN) ? (T) + 4 : T_LEN - 1) * CDIM; \
      G[0] = pR[_to]; G[1] = pW[_to]; G[2] = pK[_to];                          \
      G[3] = pV[_to]; G[4] = pA[_to]; G[5] = pB[_to]; }                        \
    s0 = s0 * SW0 + _sa * SB0 + SVV * SK0;                                     \
    s1 = s1 * SW1 + _sa * SB1 + SVV * SK1;                                     \
    f32x4 _ov = s0 * SR0 + s1 * SR1;                                           \
    pox = _ov[0] + _ov[1] + _ov[2] + _ov[3];                                   \
  } while (0)
#define SCAN_STEP_I(...) SCAN_STEP(__VA_ARGS__)
#define ASET aR0,aR1,aW0,aW1,aK0,aK1,aA0,aA1,aB0,aB1,aVV
#define BSET bR0,bR1,bW0,bW1,bK0,bK1,bA0,bA1,bB0,bB1,bVV
  SCAN_STEP_I(0, gA, ASET, BSET, true);
  SCAN_STEP_I(1, gB, BSET, ASET, false);
  for (int t = 2; t < T_LEN; t += 2) {
    SCAN_STEP_I(t, gA, ASET, BSET, false);
    SCAN_STEP_I(t + 1, gB, BSET, ASET, false);
  }
#undef SCAN_STEP
#undef SCAN_STEP_I
#undef ASET
#undef BSET
  {   // flush o_{T_LEN-1}
    float _po = pox;
    _po += __shfl_xor(_po, 8);
    _po += __shfl_xor(_po, 16);
    _po += __shfl_xor(_po, 32);
    if (lane < 8) Obp[(size_t)(T_LEN - 1) * CDIM] = _po;
  }
  float* sfp = Sf + (((size_t)(b * 32 + h)) * 64 + gv) * 64 + kk0;
  *(f32x4*)sfp = s0; *(f32x4*)(sfp + 4) = s1;
}

// ---------------- GroupNorm + bonus + gate -> bf16 A for out-proj ----------------
__global__ __launch_bounds__(256) void k_gn(
    const float* __restrict__ Ob, const float* __restrict__ Rb,
    const float* __restrict__ Kb, const float* __restrict__ Vb,
    const float* __restrict__ Gb, const float* __restrict__ rk,
    const float* __restrict__ gw, const float* __restrict__ gb2,
    unsigned short* __restrict__ Aout) {
  int gwv = blockIdx.x * 4 + (threadIdx.x >> 6);
  int lane = threadIdx.x & 63;
  int m = gwv >> 5, h = gwv & 31;
  int c = h * 64 + lane;
  size_t idx = (size_t)m * CDIM + c;
  float o = Ob[idx], r = Rb[idx], k = Kb[idx], v = Vb[idx], g = Gb[idx];
  float t1 = o, t2 = o * o, t3 = r * k * rk[c];
#pragma unroll
  for (int off = 32; off; off >>= 1) {
    t1 += __shfl_xor(t1, off);
    t2 += __shfl_xor(t2, off);
    t3 += __shfl_xor(t3, off);
  }
  float mean = t1 * (1.f / 64.f);
  float var = t2 * (1.f / 64.f) - mean * mean;
  float og = (o - mean) * rsqrtf(var + 6.4e-4f) * gw[c] + gb2[c];  // eps=1e-5*64
  og += t3 * v;
  Aout[idx] = f2bf(og * g);
}

// ---------------- launch ----------------
extern "C" void kernel_launch(void* const* d_in, const int* in_sizes, int n_in,
                              void* d_out, int out_size, void* d_ws, size_t ws_size,
                              hipStream_t stream) {
  (void)in_sizes; (void)n_in; (void)out_size; (void)ws_size;
  const float* x      = (const float*)d_in[0];
  const float* vfirst = (const float*)d_in[1];
  const float* shift  = (const float*)d_in[2];
  const float* wkv0   = (const float*)d_in[3];
  const float* xr_c   = (const float*)d_in[4];
  const float* xw_c   = (const float*)d_in[5];
  const float* xk_c   = (const float*)d_in[6];
  const float* xv_c   = (const float*)d_in[7];
  const float* xa_c   = (const float*)d_in[8];
  const float* xg_c   = (const float*)d_in[9];
  const float* w0     = (const float*)d_in[10];
  const float* w1     = (const float*)d_in[11];
  const float* w2     = (const float*)d_in[12];
  const float* a0     = (const float*)d_in[13];
  const float* a1     = (const float*)d_in[14];
  const float* a2     = (const float*)d_in[15];
  const float* v0     = (const float*)d_in[16];
  const float* v1     = (const float*)d_in[17];
  const float* v2     = (const float*)d_in[18];
  const float* g1     = (const float*)d_in[19];
  const float* g2     = (const float*)d_in[20];
  const float* k_k    = (const float*)d_in[21];
  const float* k_a    = (const float*)d_in[22];
  const float* r_k    = (const float*)d_in[23];
  const float* W_r    = (const float*)d_in[24];
  const float* W_k    = (const float*)d_in[25];
  const float* W_v    = (const float*)d_in[26];
  const float* W_o    = (const float*)d_in[27];
  const float* gn_w   = (const float*)d_in[28];
  const float* gn_b   = (const float*)d_in[29];
  char* ws = (char*)d_ws;
  auto BF = [&](size_t o) { return (unsigned short*)(ws + o); };
  auto FP = [&](size_t o) { return (float*)(ws + o); };

  // weights -> bf16 (one launch; 1048576 float4-chunks PER matrix)
  { Conv4 cb{W_r, W_k, W_v, W_o, BF(oWr), BF(oWk), BF(oWv), BF(oWo)};
    k_conv4<<<dim3(4096, 4), 256, 0, stream>>>(cb, 1048576); }
  // small weights -> transposed, zero-padded bf16 (8 jobs, one launch)
  { TpJobs jt{};
    jt.src[0] = w1; jt.dst[0] = BF(oW1T); jt.sR[0] = 2048; jt.sC[0] = 96;   jt.dR[0] = 128;  jt.dC[0] = 2048;
    jt.src[1] = a1; jt.dst[1] = BF(oA1T); jt.sR[1] = 2048; jt.sC[1] = 96;   jt.dR[1] = 128;  jt.dC[1] = 2048;
    jt.src[2] = v1; jt.dst[2] = BF(oV1T); jt.sR[2] = 2048; jt.sC[2] = 64;   jt.dR[2] = 128;  jt.dC[2] = 2048;
    jt.src[3] = g1; jt.dst[3] = BF(oG1T); jt.sR[3] = 2048; jt.sC[3] = 256;  jt.dR[3] = 256;  jt.dC[3] = 2048;
    jt.src[4] = w2; jt.dst[4] = BF(oW2T); jt.sR[4] = 96;   jt.sC[4] = 2048; jt.dR[4] = 2048; jt.dC[4] = 128;
    jt.src[5] = a2; jt.dst[5] = BF(oA2T); jt.sR[5] = 96;   jt.sC[5] = 2048; jt.dR[5] = 2048; jt.dC[5] = 128;
    jt.src[6] = v2; jt.dst[6] = BF(oV2T); jt.sR[6] = 64;   jt.sC[6] = 2048; jt.dR[6] = 2048; jt.dC[6] = 128;
    jt.src[7] = g2; jt.dst[7] = BF(oG2T); jt.sR[7] = 256;  jt.sC[7] = 2048; jt.dR[7] = 2048; jt.dC[7] = 256;
    k_tp8<<<dim3(2048, 8), 256, 0, stream>>>(jt); }
  // token shift + mixes
  k_mix<<<4096, 256, 0, stream>>>(x, shift, xr_c, xw_c, xk_c, xv_c, xa_c, xg_c,
                                  BF(oXr), BF(oXw), BF(oXk), BF(oXv), BF(oXa), BF(oXg));
  // r, k, v projections (batched via blockIdx.z)
  { GemmBatch gb{};
    gb.j[0] = {BF(oXr), BF(oWr), FP(oR), 0, 2048, 2048};
    gb.j[1] = {BF(oXk), BF(oWk), FP(oK), 0, 2048, 2048};
    gb.j[2] = {BF(oXv), BF(oWv), FP(oV), 0, 2048, 2048};
    k_gemm_nt<<<dim3(16, 16, 3), 256, 0, stream>>>(gb, 2048); }
  // low-rank stage 1 (w/a/v N=128 + gate N=256) in ONE launch, K=2048
  { GemmBatch gb{};
    gb.j[0] = {BF(oXw), BF(oW1T), BF(oHw), 2, 128, 128};   // tanh
    gb.j[1] = {BF(oXa), BF(oA1T), BF(oHa), 1, 128, 128};
    gb.j[2] = {BF(oXv), BF(oV1T), BF(oHv), 1, 128, 128};
    gb.j[3] = {BF(oXg), BF(oG1T), BF(oHg), 3, 256, 256};   // sigmoid
    k_gemm_nt<<<dim3(2, 16, 4), 256, 0, stream>>>(gb, 2048); }
  // low-rank stage 2 (K=128)
  { GemmBatch gb{};
    gb.j[0] = {BF(oHw), BF(oW2T), FP(oWW), 0, 2048, 2048};
    gb.j[1] = {BF(oHa), BF(oA2T), FP(oAA), 0, 2048, 2048};
    gb.j[2] = {BF(oHv), BF(oV2T), FP(oBB), 0, 2048, 2048};
    k_gemm_nt<<<dim3(16, 16, 3), 256, 0, stream>>>(gb, 128); }
  // gate stage 2 (K=256)
  { GemmBatch gb{};
    gb.j[0] = {BF(oHg), BF(oG2T), FP(oG), 0, 2048, 2048};
    k_gemm_nt<<<dim3(16, 16, 1), 256, 0, stream>>>(gb, 256); }
  // elementwise post (decay, a, v-blend, kk-normalize, k update)
  k_post<<<16384, 256, 0, stream>>>(FP(oK), FP(oV), FP(oWW), FP(oAA), FP(oBB),
                                    vfirst, w0, a0, v0, k_k, k_a);
  // recurrence: 512 single-wave blocks (8 v-rows each)
  k_scan<<<512, 64, 0, stream>>>(FP(oR), FP(oWW), FP(oK), FP(oV), FP(oAA), FP(oBB),
                                 wkv0, FP(oO), (float*)d_out + MC);
  // groupnorm + bonus + gate
  k_gn<<<16384, 256, 0, stream>>>(FP(oO), FP(oR), FP(oK), FP(oV), FP(oG),
                                  r_k, gn_w, gn_b, BF(oAout));
  // output projection -> d_out
  { GemmBatch gb{};
    gb.j[0] = {BF(oAout), BF(oWo), d_out, 0, 2048, 2048};
    k_gemm_nt<<<dim3(16, 16, 1), 256, 0, stream>>>(gb, 2048); }
}

// Round 14
// 587.071 us; speedup vs baseline: 1.1814x; 1.0119x over previous
//
#include <hip/hip_runtime.h>
#include <stdint.h>

typedef __attribute__((ext_vector_type(4))) float f32x4;
typedef __attribute__((ext_vector_type(8))) __bf16 bf16x8;

#define DEVINL __device__ __forceinline__

// ---------------- sizes ----------------
constexpr int T_LEN = 1024;
constexpr int CDIM  = 2048;
constexpr int MROWS = 2048;               // B*T
constexpr size_t MC = (size_t)MROWS * CDIM;

// ---------------- ws offsets (bytes) ----------------
constexpr size_t SZ_BF  = MC * 2;
constexpr size_t SZ_F32 = MC * 4;
constexpr size_t oXr  = 0;
constexpr size_t oXw  = oXr + SZ_BF;
constexpr size_t oXk  = oXw + SZ_BF;
constexpr size_t oXv  = oXk + SZ_BF;
constexpr size_t oXa  = oXv + SZ_BF;
constexpr size_t oXg  = oXa + SZ_BF;
constexpr size_t oWr  = oXg + SZ_BF;
constexpr size_t oWk  = oWr + SZ_BF;
constexpr size_t oWv  = oWk + SZ_BF;
constexpr size_t oWo  = oWv + SZ_BF;
constexpr size_t oW1T = oWo + SZ_BF;          // [128][2048] bf16 (pad rows>=96 zero)
constexpr size_t oA1T = oW1T + 524288;
constexpr size_t oV1T = oA1T + 524288;        // [128][2048] (pad>=64 zero)
constexpr size_t oG1T = oV1T + 524288;        // [256][2048]
constexpr size_t oW2T = oG1T + 1048576;       // [2048][128] (pad cols>=96 zero)
constexpr size_t oA2T = oW2T + 524288;
constexpr size_t oV2T = oA2T + 524288;
constexpr size_t oG2T = oV2T + 524288;        // [2048][256]
constexpr size_t oHw  = oG2T + 1048576;       // [2048][128] bf16
constexpr size_t oHa  = oHw + 524288;
constexpr size_t oHv  = oHa + 524288;
constexpr size_t oHg  = oHv + 524288;         // [2048][256]
constexpr size_t oR   = oHg + 1048576;        // fp32 [M][C]
constexpr size_t oK   = oR  + SZ_F32;
constexpr size_t oV   = oK  + SZ_F32;
constexpr size_t oWW  = oV  + SZ_F32;
constexpr size_t oAA  = oWW + SZ_F32;
constexpr size_t oBB  = oAA + SZ_F32;
constexpr size_t oG   = oBB + SZ_F32;
constexpr size_t oO   = oG  + SZ_F32;
constexpr size_t oAout= oO  + SZ_F32;         // bf16 [M][C]

// ---------------- helpers ----------------
DEVINL unsigned short f2bf(float f) {
  uint32_t u = __builtin_bit_cast(uint32_t, f);
  u += 0x7fffu + ((u >> 16) & 1u);            // RNE
  return (unsigned short)(u >> 16);
}
DEVINL void st_bf4(unsigned short* p, f32x4 v) {
  ushort4 o;
  o.x = f2bf(v[0]); o.y = f2bf(v[1]); o.z = f2bf(v[2]); o.w = f2bf(v[3]);
  *(ushort4*)p = o;
}
DEVINL void gload16(const void* g, void* l) {
  __builtin_amdgcn_global_load_lds(
      (const __attribute__((address_space(1))) unsigned int*)g,
      (__attribute__((address_space(3))) unsigned int*)l, 16, 0, 0);
}

// ---- VALU-speed cross-lane reduce hops (register-only; no LDS pipe) ----
// xor8 within a 16-lane row: DPP row_ror:8 (rotation by 8 mod 16 == xor 8)
DEVINL float red8(float x) {
  int y = __builtin_amdgcn_update_dpp(0, __builtin_bit_cast(int, x),
                                      0x128, 0xF, 0xF, true);
  return x + __builtin_bit_cast(float, y);
}
// xor16: v_permlane16_swap_b32 (odd rows of a <-> even rows of b). With (x,x):
// ret0=[x0,x0,x2,x2], ret1=[x1,x1,x3,x3] by 16-lane rows; partner = evenrow?ret1:ret0.
#if __has_builtin(__builtin_amdgcn_permlane16_swap)
DEVINL float red16(float x, bool evenrow) {
  unsigned xi = __builtin_bit_cast(unsigned, x);
  auto r = __builtin_amdgcn_permlane16_swap(xi, xi, false, false);
  unsigned oth = evenrow ? (unsigned)r[1] : (unsigned)r[0];
  return x + __builtin_bit_cast(float, oth);
}
#else
DEVINL float red16(float x, bool) { return x + __shfl_xor(x, 16); }
#endif
// xor32: v_permlane32_swap_b32 (upper half of a <-> lower half of b). With (x,x):
// ret0=[xlo,xlo], ret1=[xhi,xhi] by 32-lane halves; partner = lowhalf?ret1:ret0.
#if __has_builtin(__builtin_amdgcn_permlane32_swap)
DEVINL float red32(float x, bool lowhalf) {
  unsigned xi = __builtin_bit_cast(unsigned, x);
  auto r = __builtin_amdgcn_permlane32_swap(xi, xi, false, false);
  unsigned oth = lowhalf ? (unsigned)r[1] : (unsigned)r[0];
  return x + __builtin_bit_cast(float, oth);
}
#else
DEVINL float red32(float x, bool) { return x + __shfl_xor(x, 32); }
#endif

// ---------------- fp32 -> bf16 convert, 4 matrices per launch ----------------
// grid (4096, 4), n4 = 1048576 float4-chunks PER matrix (2048*2048/4).
struct Conv4 { const float* s0; const float* s1; const float* s2; const float* s3;
               unsigned short* d0; unsigned short* d1; unsigned short* d2; unsigned short* d3; };
__global__ void k_conv4(Conv4 c, int n4) {
  int i = blockIdx.x * 256 + threadIdx.x;
  if (i >= n4) return;
  const float* s = (blockIdx.y == 0) ? c.s0 : (blockIdx.y == 1) ? c.s1
                   : (blockIdx.y == 2) ? c.s2 : c.s3;
  unsigned short* d = (blockIdx.y == 0) ? c.d0 : (blockIdx.y == 1) ? c.d1
                      : (blockIdx.y == 2) ? c.d2 : c.d3;
  f32x4 v = *(const f32x4*)(s + (size_t)i * 4);
  st_bf4(d + (size_t)i * 4, v);
}

// ---------------- transpose + zero-pad, 8 jobs in one launch ----------------
struct TpJobs {
  const float* src[8];
  unsigned short* dst[8];
  int sR[8]; int sC[8]; int dR[8]; int dC[8];
};
__global__ void k_tp8(TpJobs jt) {
  const int j = blockIdx.y;
  const int n = jt.dR[j] * jt.dC[j];
  int i = blockIdx.x * 256 + threadIdx.x;
  if (i >= n) return;
  const int dC = jt.dC[j], sR = jt.sR[j], sC = jt.sC[j];
  int r = i / dC, c = i - r * dC;
  float v = (r < sC && c < sR) ? jt.src[j][(size_t)c * sC + r] : 0.f;
  jt.dst[j][i] = f2bf(v);
}

// ---------------- token shift + 6 mixes -> bf16 ----------------
__global__ void k_mix(const float* __restrict__ x, const float* __restrict__ shift,
                      const float* __restrict__ cr, const float* __restrict__ cw,
                      const float* __restrict__ ck, const float* __restrict__ cv,
                      const float* __restrict__ ca, const float* __restrict__ cg,
                      unsigned short* __restrict__ Xr, unsigned short* __restrict__ Xw,
                      unsigned short* __restrict__ Xk, unsigned short* __restrict__ Xv,
                      unsigned short* __restrict__ Xa, unsigned short* __restrict__ Xg) {
  int i = blockIdx.x * 256 + threadIdx.x;      // one float4 per thread
  size_t e = (size_t)i * 4;
  int m = (int)(e >> 11);
  int c = (int)(e & 2047);
  int t = m & (T_LEN - 1);
  int b = m >> 10;
  f32x4 xc = *(const f32x4*)(x + e);
  f32x4 pv = (t == 0) ? *(const f32x4*)(shift + (size_t)b * CDIM + c)
                      : *(const f32x4*)(x + e - CDIM);
  f32x4 xx = pv - xc;
  st_bf4(Xr + e, xc + xx * (*(const f32x4*)(cr + c)));
  st_bf4(Xw + e, xc + xx * (*(const f32x4*)(cw + c)));
  st_bf4(Xk + e, xc + xx * (*(const f32x4*)(ck + c)));
  st_bf4(Xv + e, xc + xx * (*(const f32x4*)(cv + c)));
  st_bf4(Xa + e, xc + xx * (*(const f32x4*)(ca + c)));
  st_bf4(Xg + e, xc + xx * (*(const f32x4*)(cg + c)));
}

// ---------------- NT bf16 GEMM: C[m][n] = sum_k A[m][k]*B[n][k] ----------------
// m97 structure: 128x128 tile, BK=32, linear [128][32] LDS, global_load_lds w=16,
// 2-barrier loop, 4 waves (2x2 of 64x64), mfma 16x16x32 bf16.
// Per-job ldc/n; blocks with colB >= n early-exit (lets jobs of different N batch).
struct GemmJob { const unsigned short* A; const unsigned short* B; void* C; int epi; int ldc; int n; };
struct GemmBatch { GemmJob j[4]; };

__global__ __launch_bounds__(256) void k_gemm_nt(GemmBatch gb, int K) {
  const GemmJob jb = gb.j[blockIdx.z];
  const int colB = blockIdx.x * 128;
  if (colB >= jb.n) return;
  const int ldc = jb.ldc;
  __shared__ __align__(16) unsigned short As[128 * 32];
  __shared__ __align__(16) unsigned short Bs[128 * 32];
  const int tid  = threadIdx.x;
  const int lane = tid & 63;
  const int wv   = tid >> 6;
  const int wm = wv >> 1, wn = wv & 1;
  const int rowB = blockIdx.y * 128;
  // staging: 8 chunks of 1KB (16 rows x 64B); wave wv owns chunks wv and wv+4
  const size_t rsb = (size_t)K * 2;           // row stride bytes
  const int c0 = wv, c1 = wv + 4;
  const char* Ag0 = (const char*)jb.A + (size_t)(rowB + c0 * 16 + (lane >> 2)) * rsb + (lane & 3) * 16;
  const char* Ag1 = (const char*)jb.A + (size_t)(rowB + c1 * 16 + (lane >> 2)) * rsb + (lane & 3) * 16;
  const char* Bg0 = (const char*)jb.B + (size_t)(colB + c0 * 16 + (lane >> 2)) * rsb + (lane & 3) * 16;
  const char* Bg1 = (const char*)jb.B + (size_t)(colB + c1 * 16 + (lane >> 2)) * rsb + (lane & 3) * 16;
  unsigned short* Al0 = As + c0 * 512;        // wave-uniform LDS base
  unsigned short* Al1 = As + c1 * 512;
  unsigned short* Bl0 = Bs + c0 * 512;
  unsigned short* Bl1 = Bs + c1 * 512;
  f32x4 acc[4][4];
#pragma unroll
  for (int mi = 0; mi < 4; ++mi)
#pragma unroll
    for (int ni = 0; ni < 4; ++ni) acc[mi][ni] = (f32x4){0.f, 0.f, 0.f, 0.f};
  const int KT = K >> 5;
  const int fr = lane & 15, fk = (lane >> 4) * 8;
  for (int kt = 0; kt < KT; ++kt) {
    __syncthreads();                          // prior-iter LDS reads complete
    gload16(Ag0, Al0); gload16(Ag1, Al1);
    gload16(Bg0, Bl0); gload16(Bg1, Bl1);
    Ag0 += 64; Ag1 += 64; Bg0 += 64; Bg1 += 64;
    __syncthreads();                          // drains vmcnt -> LDS tile ready
    bf16x8 af[4], bfv[4];
#pragma unroll
    for (int mi = 0; mi < 4; ++mi)
      af[mi] = *(const bf16x8*)&As[(wm * 64 + mi * 16 + fr) * 32 + fk];
#pragma unroll
    for (int ni = 0; ni < 4; ++ni)
      bfv[ni] = *(const bf16x8*)&Bs[(wn * 64 + ni * 16 + fr) * 32 + fk];
#pragma unroll
    for (int mi = 0; mi < 4; ++mi)
#pragma unroll
      for (int ni = 0; ni < 4; ++ni)
        acc[mi][ni] = __builtin_amdgcn_mfma_f32_16x16x32_bf16(af[mi], bfv[ni], acc[mi][ni], 0, 0, 0);
  }
  // epilogue: C/D layout col=lane&15, row=(lane>>4)*4+j
  const int er = (lane >> 4) * 4, ec = lane & 15;
  if (jb.epi == 0) {
    float* Cf = (float*)jb.C;
#pragma unroll
    for (int mi = 0; mi < 4; ++mi)
#pragma unroll
      for (int ni = 0; ni < 4; ++ni) {
        int row0 = rowB + wm * 64 + mi * 16 + er;
        int col  = colB + wn * 64 + ni * 16 + ec;
#pragma unroll
        for (int j = 0; j < 4; ++j)
          Cf[(size_t)(row0 + j) * ldc + col] = acc[mi][ni][j];
      }
  } else {
    unsigned short* Cb = (unsigned short*)jb.C;
#pragma unroll
    for (int mi = 0; mi < 4; ++mi)
#pragma unroll
      for (int ni = 0; ni < 4; ++ni) {
        int row0 = rowB + wm * 64 + mi * 16 + er;
        int col  = colB + wn * 64 + ni * 16 + ec;
#pragma unroll
        for (int j = 0; j < 4; ++j) {
          float val = acc[mi][ni][j];
          if (jb.epi == 2) val = tanhf(val);
          else if (jb.epi == 3) val = 1.f / (1.f + __expf(-val));
          Cb[(size_t)(row0 + j) * ldc + col] = f2bf(val);
        }
      }
  }
}

// ---------------- post-GEMM elementwise + per-head kk normalize ----------------
__global__ __launch_bounds__(256) void k_post(
    float* __restrict__ Kb, float* __restrict__ Vb, float* __restrict__ Wb,
    float* __restrict__ Ab, float* __restrict__ Bb,
    const float* __restrict__ vf, const float* __restrict__ w0,
    const float* __restrict__ a0, const float* __restrict__ v0,
    const float* __restrict__ kkc, const float* __restrict__ kac) {
  int gw = blockIdx.x * 4 + (threadIdx.x >> 6);
  int lane = threadIdx.x & 63;
  int m = gw >> 5, h = gw & 31;
  int c = h * 64 + lane;
  size_t idx = (size_t)m * CDIM + c;
  float kraw = Kb[idx], vraw = Vb[idx], wlr = Wb[idx], alr = Ab[idx], vlr = Bb[idx];
  float z = w0[c] + wlr;
  float sg = 1.f / (1.f + __expf(-z));
  float wdec = __expf(-0.60653065971f * sg);  // exp(-exp(-softplus(-z)-0.5))
  float a = 1.f / (1.f + __expf(-(a0[c] + alr)));
  float vgate = 1.f / (1.f + __expf(-(v0[c] + vlr)));
  float v = vraw + (vf[idx] - vraw) * vgate;
  float kk = kraw * kkc[c];
  float s2 = kk * kk;
#pragma unroll
  for (int off = 32; off; off >>= 1) s2 += __shfl_xor(s2, off);
  float inv = 1.f / fmaxf(sqrtf(s2), 1e-12f);
  kk *= inv;
  float kn = kraw * (1.f + (a - 1.f) * kac[c]);
  Wb[idx] = wdec; Vb[idx] = v; Kb[idx] = kn; Ab[idx] = -kk; Bb[idx] = kk * a;
}

// ---------------- RWKV-7 recurrence ----------------
// R13 skeleton (PASSING @294us) with ONE register-class delta: the two 3-hop
// reduce chains (sa, po) use VALU lane-exchange (DPP row_ror:8 + permlane16/32
// swap) instead of LDS-pipe __shfl_xor. LDS ring, staging stream, stores are
// R13-byte-identical.
__global__ __launch_bounds__(64) void k_scan(
    const float* __restrict__ Rb, const float* __restrict__ Wb,
    const float* __restrict__ Kb, const float* __restrict__ Vb,
    const float* __restrict__ Ab, const float* __restrict__ Bb,
    const float* __restrict__ S0, float* __restrict__ Ob,
    float* __restrict__ Sf) {
  const int bid = blockIdx.x;
  const int bh = bid & 63, vo = bid >> 6;     // vo stride 64 => same XCD as its head
  const int b = bh >> 5, h = bh & 31;
  const int lane = threadIdx.x;
  const int vr = lane & 7;
  const int kq = lane >> 3;
  const int gv = vo * 8 + vr;                 // global v-row in head
  const int kk0 = kq * 8;
  const bool evr = ((lane >> 4) & 1) == 0;    // even 16-lane row
  const bool lhf = lane < 32;                 // lower 32-lane half
  __shared__ __align__(16) float stg[4][6][64];
  const size_t rowBase = (size_t)b * T_LEN * CDIM;
  const size_t colBase = (size_t)h * 64;
  const float* pR = Rb + rowBase + colBase + lane;
  const float* pW = Wb + rowBase + colBase + lane;
  const float* pK = Kb + rowBase + colBase + lane;
  const float* pV = Vb + rowBase + colBase + lane;
  const float* pA = Ab + rowBase + colBase + lane;
  const float* pB = Bb + rowBase + colBase + lane;
  float* Obp = Ob + rowBase + colBase + vo * 8 + lane;   // valid for lane<8
  f32x4 s0, s1;
  {
    const float* sp = S0 + (((size_t)(b * 32 + h)) * 64 + gv) * 64 + kk0;
    s0 = *(const f32x4*)sp; s1 = *(const f32x4*)(sp + 4);
  }
  float gA[6], gB[6];
  {   // prologue: stg[0]<-t0, stg[1]<-t1, gA<-t2, gB<-t3
    float h0[6], h1[6];
    h0[0] = pR[0]; h0[1] = pW[0]; h0[2] = pK[0]; h0[3] = pV[0]; h0[4] = pA[0]; h0[5] = pB[0];
    h1[0] = pR[CDIM]; h1[1] = pW[CDIM]; h1[2] = pK[CDIM]; h1[3] = pV[CDIM]; h1[4] = pA[CDIM]; h1[5] = pB[CDIM];
#pragma unroll
    for (int j = 0; j < 6; ++j) { stg[0][j][lane] = h0[j]; stg[1][j][lane] = h1[j]; }
    gA[0] = pR[2 * CDIM]; gA[1] = pW[2 * CDIM]; gA[2] = pK[2 * CDIM];
    gA[3] = pV[2 * CDIM]; gA[4] = pA[2 * CDIM]; gA[5] = pB[2 * CDIM];
    gB[0] = pR[3 * CDIM]; gB[1] = pW[3 * CDIM]; gB[2] = pK[3 * CDIM];
    gB[3] = pV[3 * CDIM]; gB[4] = pA[3 * CDIM]; gB[5] = pB[3 * CDIM];
  }
  // operand register sets: a-set = even steps, b-set = odd steps
  f32x4 aR0, aR1, aW0, aW1, aK0, aK1, aA0, aA1, aB0, aB1; float aVV;
  f32x4 bR0, bR1, bW0, bW1, bK0, bK1, bA0, bA1, bB0, bB1; float bVV;
  // init a-set <- slot 0 (t0), written in prologue (in-order DS)
  aR0 = *(const f32x4*)&stg[0][0][kk0]; aR1 = *(const f32x4*)&stg[0][0][kk0 + 4];
  aW0 = *(const f32x4*)&stg[0][1][kk0]; aW1 = *(const f32x4*)&stg[0][1][kk0 + 4];
  aK0 = *(const f32x4*)&stg[0][2][kk0]; aK1 = *(const f32x4*)&stg[0][2][kk0 + 4];
  aA0 = *(const f32x4*)&stg[0][4][kk0]; aA1 = *(const f32x4*)&stg[0][4][kk0 + 4];
  aB0 = *(const f32x4*)&stg[0][5][kk0]; aB1 = *(const f32x4*)&stg[0][5][kk0 + 4];
  aVV = stg[0][3][gv];
  float pox = 0.f;                            // deferred o partial (prev step)
#define SCAN_STEP(T, G, SR0,SR1,SW0,SW1,SK0,SK1,SA0,SA1,SB0,SB1,SVV,           \
                  NR0,NR1,NW0,NW1,NK0,NK1,NA0,NA1,NB0,NB1,NVV, FIRST) do {     \
    f32x4 _sv = SA0 * s0 + SA1 * s1;                                           \
    float _sa = _sv[0] + _sv[1] + _sv[2] + _sv[3];                             \
    { const int _np = ((T) + 1) & 3;        /* prefetch next-step operands */  \
      NR0 = *(const f32x4*)&stg[_np][0][kk0]; NR1 = *(const f32x4*)&stg[_np][0][kk0 + 4]; \
      NW0 = *(const f32x4*)&stg[_np][1][kk0]; NW1 = *(const f32x4*)&stg[_np][1][kk0 + 4]; \
      NK0 = *(const f32x4*)&stg[_np][2][kk0]; NK1 = *(const f32x4*)&stg[_np][2][kk0 + 4]; \
      NA0 = *(const f32x4*)&stg[_np][4][kk0]; NA1 = *(const f32x4*)&stg[_np][4][kk0 + 4]; \
      NB0 = *(const f32x4*)&stg[_np][5][kk0]; NB1 = *(const f32x4*)&stg[_np][5][kk0 + 4]; \
      NVV = stg[_np][3][gv]; }                                                 \
    float _po = pox;                                                           \
    _sa = red8(_sa);        _po = red8(_po);                                   \
    _sa = red16(_sa, evr);  _po = red16(_po, evr);                             \
    _sa = red32(_sa, lhf);  _po = red32(_po, lhf);                             \
    if (!(FIRST) && lane < 8) Obp[(size_t)((T) - 1) * CDIM] = _po;             \
    { const int _ws = ((T) + 2) & 3;                                           \
      stg[_ws][0][lane] = G[0]; stg[_ws][1][lane] = G[1];                      \
      stg[_ws][2][lane] = G[2]; stg[_ws][3][lane] = G[3];                      \
      stg[_ws][4][lane] = G[4]; stg[_ws][5][lane] = G[5];                      \
      const size_t _to = (size_t)(((T) + 4 < T_LEN) ? (T) + 4 : T_LEN - 1) * CDIM; \
      G[0] = pR[_to]; G[1] = pW[_to]; G[2] = pK[_to];                          \
      G[3] = pV[_to]; G[4] = pA[_to]; G[5] = pB[_to]; }                        \
    s0 = s0 * SW0 + _sa * SB0 + SVV * SK0;                                     \
    s1 = s1 * SW1 + _sa * SB1 + SVV * SK1;                                     \
    f32x4 _ov = s0 * SR0 + s1 * SR1;                                           \
    pox = _ov[0] + _ov[1] + _ov[2] + _ov[3];                                   \
  } while (0)
#define SCAN_STEP_I(...) SCAN_STEP(__VA_ARGS__)
#define ASET aR0,aR1,aW0,aW1,aK0,aK1,aA0,aA1,aB0,aB1,aVV
#define BSET bR0,bR1,bW0,bW1,bK0,bK1,bA0,bA1,bB0,bB1,bVV
  SCAN_STEP_I(0, gA, ASET, BSET, true);
  SCAN_STEP_I(1, gB, BSET, ASET, false);
  for (int t = 2; t < T_LEN; t += 2) {
    SCAN_STEP_I(t, gA, ASET, BSET, false);
    SCAN_STEP_I(t + 1, gB, BSET, ASET, false);
  }
#undef SCAN_STEP
#undef SCAN_STEP_I
#undef ASET
#undef BSET
  {   // flush o_{T_LEN-1}
    float _po = pox;
    _po = red8(_po);
    _po = red16(_po, evr);
    _po = red32(_po, lhf);
    if (lane < 8) Obp[(size_t)(T_LEN - 1) * CDIM] = _po;
  }
  float* sfp = Sf + (((size_t)(b * 32 + h)) * 64 + gv) * 64 + kk0;
  *(f32x4*)sfp = s0; *(f32x4*)(sfp + 4) = s1;
}

// ---------------- GroupNorm + bonus + gate -> bf16 A for out-proj ----------------
__global__ __launch_bounds__(256) void k_gn(
    const float* __restrict__ Ob, const float* __restrict__ Rb,
    const float* __restrict__ Kb, const float* __restrict__ Vb,
    const float* __restrict__ Gb, const float* __restrict__ rk,
    const float* __restrict__ gw, const float* __restrict__ gb2,
    unsigned short* __restrict__ Aout) {
  int gwv = blockIdx.x * 4 + (threadIdx.x >> 6);
  int lane = threadIdx.x & 63;
  int m = gwv >> 5, h = gwv & 31;
  int c = h * 64 + lane;
  size_t idx = (size_t)m * CDIM + c;
  float o = Ob[idx], r = Rb[idx], k = Kb[idx], v = Vb[idx], g = Gb[idx];
  float t1 = o, t2 = o * o, t3 = r * k * rk[c];
#pragma unroll
  for (int off = 32; off; off >>= 1) {
    t1 += __shfl_xor(t1, off);
    t2 += __shfl_xor(t2, off);
    t3 += __shfl_xor(t3, off);
  }
  float mean = t1 * (1.f / 64.f);
  float var = t2 * (1.f / 64.f) - mean * mean;
  float og = (o - mean) * rsqrtf(var + 6.4e-4f) * gw[c] + gb2[c];  // eps=1e-5*64
  og += t3 * v;
  Aout[idx] = f2bf(og * g);
}

// ---------------- launch ----------------
extern "C" void kernel_launch(void* const* d_in, const int* in_sizes, int n_in,
                              void* d_out, int out_size, void* d_ws, size_t ws_size,
                              hipStream_t stream) {
  (void)in_sizes; (void)n_in; (void)out_size; (void)ws_size;
  const float* x      = (const float*)d_in[0];
  const float* vfirst = (const float*)d_in[1];
  const float* shift  = (const float*)d_in[2];
  const float* wkv0   = (const float*)d_in[3];
  const float* xr_c   = (const float*)d_in[4];
  const float* xw_c   = (const float*)d_in[5];
  const float* xk_c   = (const float*)d_in[6];
  const float* xv_c   = (const float*)d_in[7];
  const float* xa_c   = (const float*)d_in[8];
  const float* xg_c   = (const float*)d_in[9];
  const float* w0     = (const float*)d_in[10];
  const float* w1     = (const float*)d_in[11];
  const float* w2     = (const float*)d_in[12];
  const float* a0     = (const float*)d_in[13];
  const float* a1     = (const float*)d_in[14];
  const float* a2     = (const float*)d_in[15];
  const float* v0     = (const float*)d_in[16];
  const float* v1     = (const float*)d_in[17];
  const float* v2     = (const float*)d_in[18];
  const float* g1     = (const float*)d_in[19];
  const float* g2     = (const float*)d_in[20];
  const float* k_k    = (const float*)d_in[21];
  const float* k_a    = (const float*)d_in[22];
  const float* r_k    = (const float*)d_in[23];
  const float* W_r    = (const float*)d_in[24];
  const float* W_k    = (const float*)d_in[25];
  const float* W_v    = (const float*)d_in[26];
  const float* W_o    = (const float*)d_in[27];
  const float* gn_w   = (const float*)d_in[28];
  const float* gn_b   = (const float*)d_in[29];
  char* ws = (char*)d_ws;
  auto BF = [&](size_t o) { return (unsigned short*)(ws + o); };
  auto FP = [&](size_t o) { return (float*)(ws + o); };

  // weights -> bf16 (one launch; 1048576 float4-chunks PER matrix)
  { Conv4 cb{W_r, W_k, W_v, W_o, BF(oWr), BF(oWk), BF(oWv), BF(oWo)};
    k_conv4<<<dim3(4096, 4), 256, 0, stream>>>(cb, 1048576); }
  // small weights -> transposed, zero-padded bf16 (8 jobs, one launch)
  { TpJobs jt{};
    jt.src[0] = w1; jt.dst[0] = BF(oW1T); jt.sR[0] = 2048; jt.sC[0] = 96;   jt.dR[0] = 128;  jt.dC[0] = 2048;
    jt.src[1] = a1; jt.dst[1] = BF(oA1T); jt.sR[1] = 2048; jt.sC[1] = 96;   jt.dR[1] = 128;  jt.dC[1] = 2048;
    jt.src[2] = v1; jt.dst[2] = BF(oV1T); jt.sR[2] = 2048; jt.sC[2] = 64;   jt.dR[2] = 128;  jt.dC[2] = 2048;
    jt.src[3] = g1; jt.dst[3] = BF(oG1T); jt.sR[3] = 2048; jt.sC[3] = 256;  jt.dR[3] = 256;  jt.dC[3] = 2048;
    jt.src[4] = w2; jt.dst[4] = BF(oW2T); jt.sR[4] = 96;   jt.sC[4] = 2048; jt.dR[4] = 2048; jt.dC[4] = 128;
    jt.src[5] = a2; jt.dst[5] = BF(oA2T); jt.sR[5] = 96;   jt.sC[5] = 2048; jt.dR[5] = 2048; jt.dC[5] = 128;
    jt.src[6] = v2; jt.dst[6] = BF(oV2T); jt.sR[6] = 64;   jt.sC[6] = 2048; jt.dR[6] = 2048; jt.dC[6] = 128;
    jt.src[7] = g2; jt.dst[7] = BF(oG2T); jt.sR[7] = 256;  jt.sC[7] = 2048; jt.dR[7] = 2048; jt.dC[7] = 256;
    k_tp8<<<dim3(2048, 8), 256, 0, stream>>>(jt); }
  // token shift + mixes
  k_mix<<<4096, 256, 0, stream>>>(x, shift, xr_c, xw_c, xk_c, xv_c, xa_c, xg_c,
                                  BF(oXr), BF(oXw), BF(oXk), BF(oXv), BF(oXa), BF(oXg));
  // r, k, v projections (batched via blockIdx.z)
  { GemmBatch gb{};
    gb.j[0] = {BF(oXr), BF(oWr), FP(oR), 0, 2048, 2048};
    gb.j[1] = {BF(oXk), BF(oWk), FP(oK), 0, 2048, 2048};
    gb.j[2] = {BF(oXv), BF(oWv), FP(oV), 0, 2048, 2048};
    k_gemm_nt<<<dim3(16, 16, 3), 256, 0, stream>>>(gb, 2048); }
  // low-rank stage 1 (w/a/v N=128 + gate N=256) in ONE launch, K=2048
  { GemmBatch gb{};
    gb.j[0] = {BF(oXw), BF(oW1T), BF(oHw), 2, 128, 128};   // tanh
    gb.j[1] = {BF(oXa), BF(oA1T), BF(oHa), 1, 128, 128};
    gb.j[2] = {BF(oXv), BF(oV1T), BF(oHv), 1, 128, 128};
    gb.j[3] = {BF(oXg), BF(oG1T), BF(oHg), 3, 256, 256};   // sigmoid
    k_gemm_nt<<<dim3(2, 16, 4), 256, 0, stream>>>(gb, 2048); }
  // low-rank stage 2 (K=128)
  { GemmBatch gb{};
    gb.j[0] = {BF(oHw), BF(oW2T), FP(oWW), 0, 2048, 2048};
    gb.j[1] = {BF(oHa), BF(oA2T), FP(oAA), 0, 2048, 2048};
    gb.j[2] = {BF(oHv), BF(oV2T), FP(oBB), 0, 2048, 2048};
    k_gemm_nt<<<dim3(16, 16, 3), 256, 0, stream>>>(gb, 128); }
  // gate stage 2 (K=256)
  { GemmBatch gb{};
    gb.j[0] = {BF(oHg), BF(oG2T), FP(oG), 0, 2048, 2048};
    k_gemm_nt<<<dim3(16, 16, 1), 256, 0, stream>>>(gb, 256); }
  // elementwise post (decay, a, v-blend, kk-normalize, k update)
  k_post<<<16384, 256, 0, stream>>>(FP(oK), FP(oV), FP(oWW), FP(oAA), FP(oBB),
                                    vfirst, w0, a0, v0, k_k, k_a);
  // recurrence: 512 single-wave blocks (8 v-rows each)
  k_scan<<<512, 64, 0, stream>>>(FP(oR), FP(oWW), FP(oK), FP(oV), FP(oAA), FP(oBB),
                                 wkv0, FP(oO), (float*)d_out + MC);
  // groupnorm + bonus + gate
  k_gn<<<16384, 256, 0, stream>>>(FP(oO), FP(oR), FP(oK), FP(oV), FP(oG),
                                  r_k, gn_w, gn_b, BF(oAout));
  // output projection -> d_out
  { GemmBatch gb{};
    gb.j[0] = {BF(oAout), BF(oWo), d_out, 0, 2048, 2048};
    k_gemm_nt<<<dim3(16, 16, 1), 256, 0, stream>>>(gb, 2048); }
}